// Round 6
// baseline (262.460 us; speedup 1.0000x reference)
//
#include <hip/hip_runtime.h>

#define BGR 8
#define VG  20000
#define NK  128
#define ND  128

typedef float f32x4 __attribute__((ext_vector_type(4)));
typedef short bf16x8 __attribute__((ext_vector_type(8)));

// two fp32 -> packed 2x bf16 (RNE) in one instruction
__device__ __forceinline__ unsigned cvtpk(float a, float b) {
    unsigned r;
    asm("v_cvt_pk_bf16_f32 %0, %1, %2" : "=v"(r) : "v"(a), "v"(b));
    return r;
}

// fp32 -> bf16 bits, round-to-nearest-even (scalar, for k_coef)
__device__ __forceinline__ short bf16r(float f) {
    union { float f; unsigned u; } c; c.f = f;
    unsigned r = (c.u + 0x7FFFu + ((c.u >> 16) & 1u)) >> 16;
    return (short)r;
}

// ---------------------------------------------------------------------------
// Kernel 1: partial[bid][d][k] = sum_{v in 320-chunk} (m*x)[v,d] * E[v,k]
// DIRECT-FROM-GLOBAL fragment gather: no LDS, no pack, no barriers.
// Four prior stagings (atomics / streamed / reg ping-pong / raw-barrier) all
// pinned at ~80us with ~1 load in flight per wave: the allocator sank every
// prefetch to its use (VGPR_Count 76 vs 64 needed for buffers alone).
// Here each round is 72 INDEPENDENT loads -> deep ILP with nothing for the
// scheduler to sink past. Per (i,j) dword wave-load: lanes lo -> 16
// consecutive cols (64B segment), hi -> 4 v-rows; fully consumed, no
// within-wave duplication. Mass folded in-register before cvt_pk.
// ---------------------------------------------------------------------------
#define VC  320
#define NCH ((VG + VC - 1) / VC)   // 63 chunks: 62 full + one 160-row tail

__global__ __launch_bounds__(256) void k_spec(const float* __restrict__ x,
                                              const float* __restrict__ mass,
                                              const float* __restrict__ evecs,
                                              float* __restrict__ scr) {
    const int bid   = blockIdx.x;     // 504 = 63 chunks x 8 graphs
    const int g     = bid & 7;        // XCD pin
    const int chunk = bid >> 3;
    const int v0    = chunk * VC;
    const int nv    = (VG - v0 < VC) ? (VG - v0) : VC;   // 320 or 160
    const int rounds = nv >> 5;

    const float* xg = x     + (size_t)g * VG * ND;
    const float* eg = evecs + (size_t)g * VG * NK;
    const float* mg = mass  + (size_t)g * VG;

    const int tid = threadIdx.x;
    const int l   = tid & 63;
    const int w   = tid >> 6;
    const int lo  = l & 15, hi = l >> 4;
    const int r0  = (w & 1) * 64, c0 = (w >> 1) * 64;   // d-block, k-block

    // per-lane base pointers; imm offsets cover j*row + i*16 (<4096B)
    const float* ax = xg + (size_t)(v0 + hi * 8) * ND + r0 + lo;
    const float* be = eg + (size_t)(v0 + hi * 8) * NK + c0 + lo;
    const float* mp = mg + v0 + hi * 8;

    f32x4 acc[4][4] = {};

#pragma unroll 1
    for (int r = 0; r < rounds; ++r) {
        float mv[8], xa[4][8], eb[4][8];
#pragma unroll
        for (int j = 0; j < 8; ++j) mv[j] = mp[j];
#pragma unroll
        for (int j = 0; j < 8; ++j)
#pragma unroll
            for (int i = 0; i < 4; ++i) {
                xa[i][j] = ax[j * ND + i * 16];
                eb[i][j] = be[j * NK + i * 16];
            }

        union { uint4 u; bf16x8 v; } pa[4], pb[4];
#pragma unroll
        for (int i = 0; i < 4; ++i) {
            pa[i].u.x = cvtpk(xa[i][0] * mv[0], xa[i][1] * mv[1]);
            pa[i].u.y = cvtpk(xa[i][2] * mv[2], xa[i][3] * mv[3]);
            pa[i].u.z = cvtpk(xa[i][4] * mv[4], xa[i][5] * mv[5]);
            pa[i].u.w = cvtpk(xa[i][6] * mv[6], xa[i][7] * mv[7]);
            pb[i].u.x = cvtpk(eb[i][0], eb[i][1]);
            pb[i].u.y = cvtpk(eb[i][2], eb[i][3]);
            pb[i].u.z = cvtpk(eb[i][4], eb[i][5]);
            pb[i].u.w = cvtpk(eb[i][6], eb[i][7]);
        }
#pragma unroll
        for (int i = 0; i < 4; ++i)
#pragma unroll
            for (int j = 0; j < 4; ++j)
                acc[i][j] = __builtin_amdgcn_mfma_f32_16x16x32_bf16(pa[i].v, pb[j].v, acc[i][j], 0, 0, 0);

        ax += 32 * ND; be += 32 * NK; mp += 32;
    }

    // epilogue: streamed stores of the private partial tile [d][k]
    float* sg = scr + (size_t)bid * ND * NK;
#pragma unroll
    for (int i = 0; i < 4; ++i)
#pragma unroll
        for (int j = 0; j < 4; ++j)
#pragma unroll
            for (int t = 0; t < 4; ++t) {
                const int dd = r0 + 16 * i + hi * 4 + t;
                const int kk = c0 + 16 * j + lo;
                sg[dd * NK + kk] = acc[i][j][t];
            }
}

// ---------------------------------------------------------------------------
// Kernel 2: reduce 63 partials + apply exp(-lambda*t), write bf16 Yt[g][d][k]
// slab for (g,chunk) sits at bid = chunk*8+g -> stride 8*16384 floats
// ---------------------------------------------------------------------------
__global__ __launch_bounds__(256) void k_coef(const float* __restrict__ scr,
                                              const float* __restrict__ evals,
                                              const float* __restrict__ dt,
                                              short* __restrict__ Yt) {
    const int bid = blockIdx.x;                       // 512
    const int g   = bid & 7;
    const int rem = (bid >> 3) * 256 + threadIdx.x;   // 0..16383
    const int d   = rem >> 7;
    const int k   = rem & 127;
    const float* p = scr + (size_t)g * ND * NK + rem;
    float s = 0.f;
#pragma unroll
    for (int c = 0; c < NCH; ++c)
        s += p[(size_t)c * 8 * ND * NK];
    const float t = fmaxf(dt[d], 1e-8f);
    Yt[(size_t)g * ND * NK + rem] = bf16r(__expf(-evals[g * NK + k] * t) * s);
}

// ---------------------------------------------------------------------------
// Kernel 3: out[v,d] = sum_k E[v,k] * Yt[g][d][k]
// Zero LDS, zero barriers. B-fragments (Yt bf16, k-contiguous) are
// TILE-INVARIANT: 16 uint4 global loads once per block, held in registers
// (Yt is 32KB/graph, L2-hot from k_coef). A-fragments (evecs) are loaded
// per tile as 2x float4 per frag (k-contiguous, 16 rows x 64B per instr).
// ---------------------------------------------------------------------------
#define TV    64
#define TPB   5
#define VSPAN (TV * TPB)                    // 320
#define NBLK  ((VG + VSPAN - 1) / VSPAN)    // 63

__global__ __launch_bounds__(256) void k_out(const float* __restrict__ evecs,
                                             const short* __restrict__ Yt,
                                             float* __restrict__ out) {
    const int bid    = blockIdx.x;          // 504 = 63 spans x 8 graphs
    const int g      = bid & 7;
    const int slot   = bid >> 3;
    const int v_base = slot * VSPAN;

    const float* eg = evecs + (size_t)g * VG * NK;
    float*       og = out   + (size_t)g * VG * ND;
    const short* yg = Yt    + (size_t)g * ND * NK;

    const int tid = threadIdx.x;
    const int l   = tid & 63;
    const int w   = tid >> 6;
    const int lo  = l & 15, hi = l >> 4;
    const int r0  = (w & 1) * 32, c0 = (w >> 1) * 64;  // 32 x 64 per wave

    // tile-invariant B fragments: bv[j][ks] = Yt[d=c0+16j+lo][ks*32+hi*8 ..+7]
    bf16x8 bv[4][4];
#pragma unroll
    for (int j = 0; j < 4; ++j)
#pragma unroll
        for (int ks = 0; ks < 4; ++ks)
            bv[j][ks] = *(const bf16x8*)(yg + (c0 + 16 * j + lo) * NK + ks * 32 + hi * 8);

#pragma unroll 1
    for (int t = 0; t < TPB; ++t) {
        const int tv0 = v_base + t * TV;
        if (tv0 >= VG) break;
        const int rows = (VG - tv0 < TV) ? (VG - tv0) : TV;

        // A fragments: af[i][ks] = E[v=tv0+r0+16i+lo][k=ks*32+hi*8 ..+7]
        float4 fa[2][4][2];
#pragma unroll
        for (int i = 0; i < 2; ++i) {
            const int R  = r0 + 16 * i + lo;
            const int Rc = R < rows ? R : rows - 1;   // clamp tail OOB reads
            const float* ap = eg + (size_t)(tv0 + Rc) * NK + hi * 8;
#pragma unroll
            for (int ks = 0; ks < 4; ++ks) {
                fa[i][ks][0] = *(const float4*)(ap + ks * 32);
                fa[i][ks][1] = *(const float4*)(ap + ks * 32 + 4);
            }
        }
        union { uint4 u; bf16x8 v; } af[2][4];
#pragma unroll
        for (int i = 0; i < 2; ++i)
#pragma unroll
            for (int ks = 0; ks < 4; ++ks) {
                af[i][ks].u.x = cvtpk(fa[i][ks][0].x, fa[i][ks][0].y);
                af[i][ks].u.y = cvtpk(fa[i][ks][0].z, fa[i][ks][0].w);
                af[i][ks].u.z = cvtpk(fa[i][ks][1].x, fa[i][ks][1].y);
                af[i][ks].u.w = cvtpk(fa[i][ks][1].z, fa[i][ks][1].w);
            }

        f32x4 acc[2][4] = {};
#pragma unroll
        for (int ks = 0; ks < 4; ++ks)
#pragma unroll
            for (int i = 0; i < 2; ++i)
#pragma unroll
                for (int j = 0; j < 4; ++j)
                    acc[i][j] = __builtin_amdgcn_mfma_f32_16x16x32_bf16(af[i][ks].v, bv[j][ks], acc[i][j], 0, 0, 0);

#pragma unroll
        for (int i = 0; i < 2; ++i)
#pragma unroll
            for (int j = 0; j < 4; ++j)
#pragma unroll
                for (int u = 0; u < 4; ++u) {
                    const int vv = r0 + 16 * i + hi * 4 + u;
                    if (vv < rows)
                        og[(size_t)(tv0 + vv) * ND + c0 + 16 * j + lo] = acc[i][j][u];
                }
    }
}

extern "C" void kernel_launch(void* const* d_in, const int* in_sizes, int n_in,
                              void* d_out, int out_size, void* d_ws, size_t ws_size,
                              hipStream_t stream) {
    const float* x     = (const float*)d_in[0];
    const float* mass  = (const float*)d_in[1];
    const float* evals = (const float*)d_in[2];
    const float* evecs = (const float*)d_in[3];
    const float* dt    = (const float*)d_in[4];
    // d_in[5] = batch (unused: equal-sized graphs), d_in[6] = bs (compile-time 8)
    float* out = (float*)d_out;

    // partials live in the OUTPUT buffer (504*64KB = 31.5MB <= 82MB), fully
    // overwritten by k_out afterwards; Yt (256KB) lives in the workspace
    float* scr = out;
    short* Yt  = (short*)d_ws;

    k_spec<<<NCH * BGR, 256, 0, stream>>>(x, mass, evecs, scr);
    k_coef<<<(BGR * ND * NK) / 256, 256, 0, stream>>>(scr, evals, dt, Yt);
    k_out<<<NBLK * BGR, 256, 0, stream>>>(evecs, Yt, out);
}